// Round 14
// baseline (11628.345 us; speedup 1.0000x reference)
//
#include <hip/hip_runtime.h>
#include <hip/hip_bf16.h>

#define B_SZ 16384
#define T_SZ 20

typedef __attribute__((ext_vector_type(8))) __bf16 bf16x8;
typedef __attribute__((ext_vector_type(4))) float f32x4;

__device__ __forceinline__ float sigm(float x){ return 1.f/(1.f+__expf(-x)); }
__device__ __forceinline__ float tanh_(float x){ return 1.f-2.f/(__expf(2.f*x)+1.f); }

// packed weight element offsets (bf16 elements)
#define OFF_L1Z2 0
#define OFF_L2Z2 360448
#define OFF_L1Z1 884736
#define OFF_L2Z1 1277952
#define OFF_HZ2  1802240
#define OFF_HZ1  1835008
#define WP_TOT   1867776

// ---------------- weight prep (4-wgn layout, proven, unchanged) ----------------
__global__ void prep_w(const float* __restrict__ W0, const float* __restrict__ U0,
                       const float* __restrict__ W1, const float* __restrict__ U1,
                       const float* __restrict__ W2, const float* __restrict__ U2,
                       const float* __restrict__ W3, const float* __restrict__ U3,
                       const float* __restrict__ muW2, const float* __restrict__ lvW2,
                       const float* __restrict__ muW1, const float* __restrict__ lvW1,
                       __bf16* __restrict__ wp)
{
    int idx = blockIdx.x * 256 + threadIdx.x;
    if (idx >= WP_TOT) return;
    if (idx < OFF_HZ2) {
        const float *W, *U;
        int Fx, Kx, KT, local;
        if (idx < OFF_L2Z2)      { W = W0; U = U0; Fx = 80;  Kx = 96;  KT = 11; local = idx; }
        else if (idx < OFF_L1Z1) { W = W1; U = U1; Fx = 256; Kx = 256; KT = 16; local = idx - OFF_L2Z2; }
        else if (idx < OFF_L2Z1) { W = W2; U = U2; Fx = 112; Kx = 128; KT = 12; local = idx - OFF_L1Z1; }
        else                     { W = W3; U = U3; Fx = 256; Kx = 256; KT = 16; local = idx - OFF_L2Z1; }
        int jj = local & 7, lane = (local >> 3) & 63, nt16 = (local >> 9) & 15, rest = local >> 13;
        int kt = rest % KT, wgn = rest / KT;
        int gate = nt16 & 3, hh = nt16 >> 2;
        int n = gate * 256 + wgn * 64 + hh * 16 + (lane & 15);
        int k = kt * 32 + ((lane >> 4) << 3) + jj;
        float v = (k < Fx) ? W[k * 1024 + n] : (k < Kx ? 0.f : U[(k - Kx) * 1024 + n]);
        wp[idx] = (__bf16)v;
    } else {
        int base = (idx < OFF_HZ1) ? OFF_HZ2 : OFF_HZ1;
        const float* mw = (idx < OFF_HZ1) ? muW2 : muW1;
        const float* lw = (idx < OFF_HZ1) ? lvW2 : lvW1;
        int local = idx - base;
        int jj = local & 7, lane = (local >> 3) & 63, nt = (local >> 9) & 3, kt = local >> 11;
        int k = kt * 32 + ((lane >> 4) << 3) + jj;
        int c16 = lane & 15;
        float v = (nt < 2) ? mw[k * 32 + nt * 16 + c16] : lw[k * 32 + (nt - 2) * 16 + c16];
        wp[idx] = (__bf16)v;
    }
}

// ---------------- x fp32 -> xF bf16 A-fragment layout ----------------
// xF[((R*T + t)*4 + kt)*512 + l*8 + j] = x_pad[R*16 + (l&15)][t][kt*32 + (l>>4)*8 + j]
// (features >= 80 zero; z2-sample broadcast overwrites cols 80..111 later)
__global__ void xfrag_k(const float* __restrict__ x, __bf16* __restrict__ xF)
{
    int idx = blockIdx.x * 256 + threadIdx.x;          // ((R*20 + t)*4 + kt)*64 + l
    int l = idx & 63, kt = (idx >> 6) & 3;
    int rt = idx >> 8;                                  // R*20 + t
    int t = rt % 20, R = rt / 20;
    int row = R * 16 + (l & 15);
    int f0 = kt * 32 + ((l >> 4) << 3);
    bf16x8 r;
    if (f0 < 80) {
        const float4* p = reinterpret_cast<const float4*>(x + ((size_t)row * T_SZ + t) * 80 + f0);
        float4 u0 = p[0], u1 = p[1];
        r[0]=(__bf16)u0.x; r[1]=(__bf16)u0.y; r[2]=(__bf16)u0.z; r[3]=(__bf16)u0.w;
        r[4]=(__bf16)u1.x; r[5]=(__bf16)u1.y; r[6]=(__bf16)u1.z; r[7]=(__bf16)u1.w;
    } else {
#pragma unroll
        for (int i = 0; i < 8; ++i) r[i] = (__bf16)0.f;
    }
    *reinterpret_cast<bf16x8*>(xF + (size_t)idx * 8) = r;
}

// ---------------- broadcast z2 sample into xF cols 80..111 for all t ----------------
__global__ void bcast_z2F(const __bf16* __restrict__ z2sb, __bf16* __restrict__ xF)
{
    int idx = blockIdx.x * 256 + threadIdx.x;          // b*20 + t
    int t = idx % 20, b = idx / 20;
    int R = b >> 4, r = b & 15;
    const bf16x8* zp = reinterpret_cast<const bf16x8*>(z2sb + (size_t)b * 32);
    __bf16* base = xF + ((size_t)(R * 20 + t) * 4) * 512;
    *reinterpret_cast<bf16x8*>(base + 2 * 512 + (32 + r) * 8) = zp[0];  // cols 80-87
    *reinterpret_cast<bf16x8*>(base + 2 * 512 + (48 + r) * 8) = zp[1];  // cols 88-95
    *reinterpret_cast<bf16x8*>(base + 3 * 512 + (0  + r) * 8) = zp[2];  // cols 96-103
    *reinterpret_cast<bf16x8*>(base + 3 * 512 + (16 + r) * 8) = zp[3];  // cols 104-111
}

// ---------------- LDS-free, barrier-free LSTM-layer GEMM + cell ----------------
// wg tile 256 rows x 256 packed cols; block 512 = 8 waves (wr 0..1, wc 0..3);
// bidh = wgn*64 + mid.  A operands (x, h) stored in fragment layout -> every A load is a
// coalesced 1KB/wave global read (L2-resident).  No LDS, no barriers, no waitcnt asm:
// 16 independent waves/CU of load+MFMA dataflow, compiler-pipelined.
// h fragment layout: hF[(R*8 + kt)*512 + l*8 + j] = h[R*16+(l&15)][kt*32+(l>>4)*8+j].
// c state in fragment buffer cF (thread-contiguous f32x4).
template <int KT, int KTP, int XKT, int TWOH, int FIRST>
__device__ __forceinline__ void gemm_nolds(const __bf16* __restrict__ xF, int t,
          const __bf16* __restrict__ hAF, const __bf16* __restrict__ hBF,
          const __bf16* __restrict__ wpm, const float* __restrict__ bias,
          float* __restrict__ cF, float* __restrict__ crow, __bf16* __restrict__ hOF,
          int bidh, int writeCrow)
{
    const int tid = threadIdx.x;
    const int w = tid >> 6, lane = tid & 63;
    const int r16 = lane & 15, kq = lane >> 4;
    const int wr = w >> 2, wc = w & 3;
    const int mid = bidh & 63, wgn = bidh >> 6;
    const int rb = mid * 256;
    const int R0 = mid * 16 + wr * 8;                  // fragment row-group base (+m)

    const __bf16* pBW = wpm + (size_t)wgn * KTP * 8192 + wc * 2048 + lane * 8;
    const __bf16* axb = xF + (((size_t)R0 * T_SZ + t) * 4) * 512 + lane * 8;   // + m*(T*2048) + kt*512
    const __bf16* ahb = hAF + (size_t)R0 * 4096 + lane * 8;                    // + m*4096 + kt*512
    const __bf16* ah2b = TWOH ? hBF + (size_t)R0 * 4096 + lane * 8 : ahb;

    f32x4 acc[4][8];
#pragma unroll
    for (int g = 0; g < 4; ++g)
#pragma unroll
        for (int m = 0; m < 8; ++m) acc[g][m] = f32x4{0.f, 0.f, 0.f, 0.f};

#pragma unroll
    for (int kt = 0; kt < KT; ++kt) {
        bf16x8 b0 = *reinterpret_cast<const bf16x8*>(pBW + (size_t)kt * 8192);
        bf16x8 b1 = *reinterpret_cast<const bf16x8*>(pBW + (size_t)kt * 8192 + 512);
        bf16x8 b2 = *reinterpret_cast<const bf16x8*>(pBW + (size_t)kt * 8192 + 1024);
        bf16x8 b3 = *reinterpret_cast<const bf16x8*>(pBW + (size_t)kt * 8192 + 1536);
#pragma unroll
        for (int m = 0; m < 8; ++m) {
            const __bf16* ap;
            if (kt < XKT)                    ap = axb + (size_t)m * (T_SZ * 2048) + kt * 512;
            else if (!TWOH || kt - XKT < 8)  ap = ahb + (size_t)m * 4096 + (kt - XKT) * 512;
            else                             ap = ah2b + (size_t)m * 4096 + (kt - XKT - 8) * 512;
            bf16x8 am = *reinterpret_cast<const bf16x8*>(ap);
            acc[0][m] = __builtin_amdgcn_mfma_f32_16x16x32_bf16(am, b0, acc[0][m], 0, 0, 0);
            acc[1][m] = __builtin_amdgcn_mfma_f32_16x16x32_bf16(am, b1, acc[1][m], 0, 0, 0);
            acc[2][m] = __builtin_amdgcn_mfma_f32_16x16x32_bf16(am, b2, acc[2][m], 0, 0, 0);
            acc[3][m] = __builtin_amdgcn_mfma_f32_16x16x32_bf16(am, b3, acc[3][m], 0, 0, 0);
        }
    }

    // ---- fused LSTM cell epilogue ----
    const int hcol = wgn * 64 + wc * 16 + r16;
    float bg[4];
#pragma unroll
    for (int g = 0; g < 4; ++g) bg[g] = bias[g * 256 + hcol];

    float* cf = cF + ((size_t)bidh * 512 + tid) * 32;
    const int kth = hcol >> 5;
    const int lh  = ((hcol >> 3) & 3) * 16;
    const int jh  = r16 & 7;

#pragma unroll
    for (int m = 0; m < 8; ++m) {
        f32x4 zi = acc[0][m], zf = acc[1][m], zg = acc[2][m], zo = acc[3][m];
        f32x4 co;
        if (!FIRST) co = *reinterpret_cast<f32x4*>(cf + m * 4);
        f32x4 cn;
#pragma unroll
        for (int q = 0; q < 4; ++q) {
            if (FIRST) cn[q] = sigm(zi[q] + bg[0]) * tanh_(zg[q] + bg[2]);
            else       cn[q] = sigm(zf[q] + bg[1]) * co[q]
                             + sigm(zi[q] + bg[0]) * tanh_(zg[q] + bg[2]);
            float hv = sigm(zo[q] + bg[3]) * tanh_(cn[q]);
            hOF[((size_t)(R0 + m) * 8 + kth) * 512 + (lh + kq * 4 + q) * 8 + jh] = (__bf16)hv;
            if (writeCrow) {
                int row = rb + wr * 128 + m * 16 + kq * 4 + q;
                crow[(size_t)row * 256 + hcol] = cn[q];
            }
        }
        *reinterpret_cast<f32x4*>(cf + m * 4) = cn;
    }
}

// ---------------- fused step: L2(t) and L1(t+1) are independent given h1(t) ----------------
// PHASE 0: grid 256 — L1(0) only (KT=XKT, FIRST).
// PHASE 1: grid 512 — blocks [0,256) L2(t) (KT=8 if FIRST2 else 16); blocks [256,512) L1(t+1).
// PHASE 2: grid 256 — L2(19) only (writes c2 row-major).
template <int XKT, int KT1, int PHASE, int FIRST2>
__global__ void __launch_bounds__(512, 4)
fused_step(const __bf16* __restrict__ xF, int t,
           const __bf16* __restrict__ h1cur, __bf16* __restrict__ h1nxt,
           const __bf16* __restrict__ h2prv, __bf16* __restrict__ h2cur,
           const __bf16* __restrict__ wp1, const __bf16* __restrict__ wp2,
           const float* __restrict__ b1, const float* __restrict__ b2,
           float* __restrict__ c1F, float* __restrict__ c2F,
           float* __restrict__ c1r, float* __restrict__ c2r)
{
    const int bidh = blockIdx.x & 255;

    if constexpr (PHASE == 0) {
        gemm_nolds<XKT, KT1, XKT, 0, 1>(xF, t + 1, h1cur, nullptr, wp1, b1,
                                        c1F, c1r, h1nxt, bidh, 0);
    } else if constexpr (PHASE == 2) {
        gemm_nolds<16, 16, 0, 1, 0>(xF, t, h1cur, h2prv, wp2, b2,
                                    c2F, c2r, h2cur, bidh, 1);
    } else {
        if ((blockIdx.x >> 8) == 0) {
            constexpr int KT2 = FIRST2 ? 8 : 16;
            gemm_nolds<KT2, 16, 0, 1, FIRST2>(xF, t, h1cur, h2prv, wp2, b2,
                                              c2F, c2r, h2cur, bidh, 0);
        } else {
            gemm_nolds<KT1, KT1, XKT, 0, 0>(xF, t + 1, h1cur, nullptr, wp1, b1,
                                            c1F, c1r, h1nxt, bidh, t + 1 == T_SZ - 1);
        }
    }
}

// ---------------- MFMA head (unchanged; reads row-major c) ----------------
__global__ void __launch_bounds__(128, 4)
head_mfma(const float* __restrict__ c1, const float* __restrict__ c2,
          const __bf16* __restrict__ hp, const float* __restrict__ mub,
          const float* __restrict__ lvb, const float* __restrict__ eps,
          float* __restrict__ omu, float* __restrict__ olv, float* __restrict__ osm,
          __bf16* __restrict__ osb)
{
    const int tid = threadIdx.x;
    const int w = tid >> 6, lane = tid & 63;
    const int r16 = lane & 15, kq = lane >> 4;
    const int rb = blockIdx.x * 64 + w * 32;

    f32x4 acc[4][2];
#pragma unroll
    for (int nt = 0; nt < 4; ++nt)
#pragma unroll
        for (int m = 0; m < 2; ++m) acc[nt][m] = f32x4{0.f, 0.f, 0.f, 0.f};

#pragma unroll
    for (int kt = 0; kt < 16; ++kt) {
        const float* cs = (kt < 8) ? c1 : c2;
        int k = (kt & 7) * 32 + kq * 8;
        bf16x8 a[2];
#pragma unroll
        for (int m = 0; m < 2; ++m) {
            const float* pr = cs + (size_t)(rb + m * 16 + r16) * 256 + k;
            float4 u0 = reinterpret_cast<const float4*>(pr)[0];
            float4 u1 = reinterpret_cast<const float4*>(pr)[1];
            a[m][0]=(__bf16)u0.x; a[m][1]=(__bf16)u0.y; a[m][2]=(__bf16)u0.z; a[m][3]=(__bf16)u0.w;
            a[m][4]=(__bf16)u1.x; a[m][5]=(__bf16)u1.y; a[m][6]=(__bf16)u1.z; a[m][7]=(__bf16)u1.w;
        }
        const __bf16* hb = hp + kt * 2048 + lane * 8;
#pragma unroll
        for (int nt = 0; nt < 4; ++nt) {
            bf16x8 bv = *reinterpret_cast<const bf16x8*>(hb + nt * 512);
            acc[nt][0] = __builtin_amdgcn_mfma_f32_16x16x32_bf16(a[0], bv, acc[nt][0], 0, 0, 0);
            acc[nt][1] = __builtin_amdgcn_mfma_f32_16x16x32_bf16(a[1], bv, acc[nt][1], 0, 0, 0);
        }
    }

#pragma unroll
    for (int m = 0; m < 2; ++m)
#pragma unroll
        for (int q = 0; q < 4; ++q) {
            int row = rb + m * 16 + kq * 4 + q;
#pragma unroll
            for (int z = 0; z < 2; ++z) {
                int zc = z * 16 + r16;
                float mu = acc[z][m][q] + mub[zc];
                float lv = acc[z + 2][m][q] + lvb[zc];
                int idx = row * 32 + zc;
                omu[idx] = mu;
                olv[idx] = lv;
                float s = fmaf(eps[idx], expf(0.5f * lv), mu);
                osm[idx] = s;
                if (osb) osb[idx] = (__bf16)s;
            }
        }
}

extern "C" void kernel_launch(void* const* d_in, const int* in_sizes, int n_in,
                              void* d_out, int out_size, void* d_ws, size_t ws_size,
                              hipStream_t stream)
{
    const float* x    = (const float*)d_in[0];
    const float* eps1 = (const float*)d_in[1];
    const float* eps2 = (const float*)d_in[2];
    const float* z2W1 = (const float*)d_in[3];
    const float* z2U1 = (const float*)d_in[4];
    const float* z2b1 = (const float*)d_in[5];
    const float* z2W2 = (const float*)d_in[6];
    const float* z2U2 = (const float*)d_in[7];
    const float* z2b2 = (const float*)d_in[8];
    const float* z1W1 = (const float*)d_in[9];
    const float* z1U1 = (const float*)d_in[10];
    const float* z1b1 = (const float*)d_in[11];
    const float* z1W2 = (const float*)d_in[12];
    const float* z1U2 = (const float*)d_in[13];
    const float* z1b2 = (const float*)d_in[14];
    const float* mu2W = (const float*)d_in[15];
    const float* mu2b = (const float*)d_in[16];
    const float* lv2W = (const float*)d_in[17];
    const float* lv2b = (const float*)d_in[18];
    const float* mu1W = (const float*)d_in[19];
    const float* mu1b = (const float*)d_in[20];
    const float* lv1W = (const float*)d_in[21];
    const float* lv1b = (const float*)d_in[22];

    char* ws = (char*)d_ws;
    __bf16* wp   = (__bf16*)ws;                        // 3.74 MB
    __bf16* z2sb = (__bf16*)(ws + 4194304);            // 1 MB
    __bf16* xF   = (__bf16*)(ws + 5242880);            // 84 MB fragment-layout x
    __bf16* h1Fa = (__bf16*)(ws + 89128960);           // 8 MB each (fragment-layout h)
    __bf16* h1Fb = (__bf16*)(ws + 97517568);
    __bf16* h2Fa = (__bf16*)(ws + 105906176);
    __bf16* h2Fb = (__bf16*)(ws + 114294784);
    float*  c1F  = (float*)(ws + 122683392);           // fragment c, 16 MB each
    float*  c2F  = (float*)(ws + 139460608);
    float*  c1r  = (float*)(ws + 156237824);           // row-major c for heads
    float*  c2r  = (float*)(ws + 173015040);           // end 189,792,256

    __bf16* h1[2] = {h1Fa, h1Fb};
    __bf16* h2[2] = {h2Fa, h2Fb};

    float* out = (float*)d_out;
    const int BZ = B_SZ * 32;
    float* z1mu = out;           float* z1lv = out + BZ;     float* z1sm = out + 2 * BZ;
    float* z2mu = out + 3 * BZ;  float* z2lv = out + 4 * BZ; float* z2sm = out + 5 * BZ;

    xfrag_k<<<20480, 256, 0, stream>>>(x, xF);
    prep_w<<<7296, 256, 0, stream>>>(z2W1, z2U1, z2W2, z2U2, z1W1, z1U1, z1W2, z1U2,
                                     mu2W, lv2W, mu1W, lv1W, wp);

    // ---- z2 branch (XKT=3, KT1=11) ----
    {
        const __bf16* wpa = wp + OFF_L1Z2;
        const __bf16* wpb = wp + OFF_L2Z2;
        fused_step<3, 11, 0, 0><<<256, 512, 0, stream>>>(xF, -1, h1[0], h1[0], h2[0], h2[0],
                                                         wpa, wpb, z2b1, z2b2, c1F, c2F, c1r, c2r);
        fused_step<3, 11, 1, 1><<<512, 512, 0, stream>>>(xF, 0, h1[0], h1[1], h2[1], h2[0],
                                                         wpa, wpb, z2b1, z2b2, c1F, c2F, c1r, c2r);
        for (int t = 1; t < T_SZ - 1; ++t)
            fused_step<3, 11, 1, 0><<<512, 512, 0, stream>>>(xF, t, h1[t & 1], h1[(t + 1) & 1],
                                                             h2[(t + 1) & 1], h2[t & 1],
                                                             wpa, wpb, z2b1, z2b2, c1F, c2F, c1r, c2r);
        fused_step<3, 11, 2, 0><<<256, 512, 0, stream>>>(xF, 19, h1[1], h1[0], h2[0], h2[1],
                                                         wpa, wpb, z2b1, z2b2, c1F, c2F, c1r, c2r);
    }
    head_mfma<<<256, 128, 0, stream>>>(c1r, c2r, wp + OFF_HZ2, mu2b, lv2b, eps2,
                                       z2mu, z2lv, z2sm, z2sb);
    bcast_z2F<<<1280, 256, 0, stream>>>(z2sb, xF);

    // ---- z1 branch (XKT=4, KT1=12) ----
    {
        const __bf16* wpa = wp + OFF_L1Z1;
        const __bf16* wpb = wp + OFF_L2Z1;
        fused_step<4, 12, 0, 0><<<256, 512, 0, stream>>>(xF, -1, h1[0], h1[0], h2[0], h2[0],
                                                         wpa, wpb, z1b1, z1b2, c1F, c2F, c1r, c2r);
        fused_step<4, 12, 1, 1><<<512, 512, 0, stream>>>(xF, 0, h1[0], h1[1], h2[1], h2[0],
                                                         wpa, wpb, z1b1, z1b2, c1F, c2F, c1r, c2r);
        for (int t = 1; t < T_SZ - 1; ++t)
            fused_step<4, 12, 1, 0><<<512, 512, 0, stream>>>(xF, t, h1[t & 1], h1[(t + 1) & 1],
                                                             h2[(t + 1) & 1], h2[t & 1],
                                                             wpa, wpb, z1b1, z1b2, c1F, c2F, c1r, c2r);
        fused_step<4, 12, 2, 0><<<256, 512, 0, stream>>>(xF, 19, h1[1], h1[0], h2[0], h2[1],
                                                         wpa, wpb, z1b1, z1b2, c1F, c2F, c1r, c2r);
    }
    head_mfma<<<256, 128, 0, stream>>>(c1r, c2r, wp + OFF_HZ1, mu1b, lv1b, eps1,
                                       z1mu, z1lv, z1sm, nullptr);
}

// Round 15
// 3265.521 us; speedup vs baseline: 3.5609x; 3.5609x over previous
//
#include <hip/hip_runtime.h>
#include <hip/hip_bf16.h>

#define B_SZ 16384
#define T_SZ 20

typedef __attribute__((ext_vector_type(8))) __bf16 bf16x8;
typedef __attribute__((ext_vector_type(4))) float f32x4;

__device__ __forceinline__ float sigm(float x){ return 1.f/(1.f+__expf(-x)); }
__device__ __forceinline__ float tanh_(float x){ return 1.f-2.f/(__expf(2.f*x)+1.f); }

// packed weight element offsets (bf16 elements)
#define OFF_L1Z2 0
#define OFF_L2Z2 360448
#define OFF_L1Z1 884736
#define OFF_L2Z1 1277952
#define OFF_HZ2  1802240
#define OFF_HZ1  1835008
#define WP_TOT   1867776

// ---------------- weight prep (4-wgn layout, proven, unchanged) ----------------
__global__ void prep_w(const float* __restrict__ W0, const float* __restrict__ U0,
                       const float* __restrict__ W1, const float* __restrict__ U1,
                       const float* __restrict__ W2, const float* __restrict__ U2,
                       const float* __restrict__ W3, const float* __restrict__ U3,
                       const float* __restrict__ muW2, const float* __restrict__ lvW2,
                       const float* __restrict__ muW1, const float* __restrict__ lvW1,
                       __bf16* __restrict__ wp)
{
    int idx = blockIdx.x * 256 + threadIdx.x;
    if (idx >= WP_TOT) return;
    if (idx < OFF_HZ2) {
        const float *W, *U;
        int Fx, Kx, KT, local;
        if (idx < OFF_L2Z2)      { W = W0; U = U0; Fx = 80;  Kx = 96;  KT = 11; local = idx; }
        else if (idx < OFF_L1Z1) { W = W1; U = U1; Fx = 256; Kx = 256; KT = 16; local = idx - OFF_L2Z2; }
        else if (idx < OFF_L2Z1) { W = W2; U = U2; Fx = 112; Kx = 128; KT = 12; local = idx - OFF_L1Z1; }
        else                     { W = W3; U = U3; Fx = 256; Kx = 256; KT = 16; local = idx - OFF_L2Z1; }
        int jj = local & 7, lane = (local >> 3) & 63, nt16 = (local >> 9) & 15, rest = local >> 13;
        int kt = rest % KT, wgn = rest / KT;
        int gate = nt16 & 3, hh = nt16 >> 2;
        int n = gate * 256 + wgn * 64 + hh * 16 + (lane & 15);
        int k = kt * 32 + ((lane >> 4) << 3) + jj;
        float v = (k < Fx) ? W[k * 1024 + n] : (k < Kx ? 0.f : U[(k - Kx) * 1024 + n]);
        wp[idx] = (__bf16)v;
    } else {
        int base = (idx < OFF_HZ1) ? OFF_HZ2 : OFF_HZ1;
        const float* mw = (idx < OFF_HZ1) ? muW2 : muW1;
        const float* lw = (idx < OFF_HZ1) ? lvW2 : lvW1;
        int local = idx - base;
        int jj = local & 7, lane = (local >> 3) & 63, nt = (local >> 9) & 3, kt = local >> 11;
        int k = kt * 32 + ((lane >> 4) << 3) + jj;
        int c16 = lane & 15;
        float v = (nt < 2) ? mw[k * 32 + nt * 16 + c16] : lw[k * 32 + (nt - 2) * 16 + c16];
        wp[idx] = (__bf16)v;
    }
}

// ---------------- x fp32 -> xF bf16 A-fragment layout ----------------
// xF[((R*T + t)*4 + kt)*512 + l*8 + j] = x_pad[R*16 + (l&15)][t][kt*32 + (l>>4)*8 + j]
__global__ void xfrag_k(const float* __restrict__ x, __bf16* __restrict__ xF)
{
    int idx = blockIdx.x * 256 + threadIdx.x;          // ((R*20 + t)*4 + kt)*64 + l
    int l = idx & 63, kt = (idx >> 6) & 3;
    int rt = idx >> 8;                                  // R*20 + t
    int t = rt % 20, R = rt / 20;
    int row = R * 16 + (l & 15);
    int f0 = kt * 32 + ((l >> 4) << 3);
    bf16x8 r;
    if (f0 < 80) {
        const float4* p = reinterpret_cast<const float4*>(x + ((size_t)row * T_SZ + t) * 80 + f0);
        float4 u0 = p[0], u1 = p[1];
        r[0]=(__bf16)u0.x; r[1]=(__bf16)u0.y; r[2]=(__bf16)u0.z; r[3]=(__bf16)u0.w;
        r[4]=(__bf16)u1.x; r[5]=(__bf16)u1.y; r[6]=(__bf16)u1.z; r[7]=(__bf16)u1.w;
    } else {
#pragma unroll
        for (int i = 0; i < 8; ++i) r[i] = (__bf16)0.f;
    }
    *reinterpret_cast<bf16x8*>(xF + (size_t)idx * 8) = r;
}

// ---------------- broadcast z2 sample into xF cols 80..111 for all t ----------------
__global__ void bcast_z2F(const __bf16* __restrict__ z2sb, __bf16* __restrict__ xF)
{
    int idx = blockIdx.x * 256 + threadIdx.x;          // b*20 + t
    int t = idx % 20, b = idx / 20;
    int R = b >> 4, r = b & 15;
    const bf16x8* zp = reinterpret_cast<const bf16x8*>(z2sb + (size_t)b * 32);
    __bf16* base = xF + ((size_t)(R * 20 + t) * 4) * 512;
    *reinterpret_cast<bf16x8*>(base + 2 * 512 + (32 + r) * 8) = zp[0];  // cols 80-87
    *reinterpret_cast<bf16x8*>(base + 2 * 512 + (48 + r) * 8) = zp[1];  // cols 88-95
    *reinterpret_cast<bf16x8*>(base + 3 * 512 + (0  + r) * 8) = zp[2];  // cols 96-103
    *reinterpret_cast<bf16x8*>(base + 3 * 512 + (16 + r) * 8) = zp[3];  // cols 104-111
}

// ---------------- LDS-free, barrier-free LSTM-layer GEMM + cell ----------------
// Identical to round 14 except the launch bound (VGPR cliff fix).
template <int KT, int KTP, int XKT, int TWOH, int FIRST>
__device__ __forceinline__ void gemm_nolds(const __bf16* __restrict__ xF, int t,
          const __bf16* __restrict__ hAF, const __bf16* __restrict__ hBF,
          const __bf16* __restrict__ wpm, const float* __restrict__ bias,
          float* __restrict__ cF, float* __restrict__ crow, __bf16* __restrict__ hOF,
          int bidh, int writeCrow)
{
    const int tid = threadIdx.x;
    const int w = tid >> 6, lane = tid & 63;
    const int r16 = lane & 15, kq = lane >> 4;
    const int wr = w >> 2, wc = w & 3;
    const int mid = bidh & 63, wgn = bidh >> 6;
    const int rb = mid * 256;
    const int R0 = mid * 16 + wr * 8;                  // fragment row-group base (+m)

    const __bf16* pBW = wpm + (size_t)wgn * KTP * 8192 + wc * 2048 + lane * 8;
    const __bf16* axb = xF + (((size_t)R0 * T_SZ + t) * 4) * 512 + lane * 8;
    const __bf16* ahb = hAF + (size_t)R0 * 4096 + lane * 8;
    const __bf16* ah2b = TWOH ? hBF + (size_t)R0 * 4096 + lane * 8 : ahb;

    f32x4 acc[4][8];
#pragma unroll
    for (int g = 0; g < 4; ++g)
#pragma unroll
        for (int m = 0; m < 8; ++m) acc[g][m] = f32x4{0.f, 0.f, 0.f, 0.f};

#pragma unroll
    for (int kt = 0; kt < KT; ++kt) {
        bf16x8 b0 = *reinterpret_cast<const bf16x8*>(pBW + (size_t)kt * 8192);
        bf16x8 b1 = *reinterpret_cast<const bf16x8*>(pBW + (size_t)kt * 8192 + 512);
        bf16x8 b2 = *reinterpret_cast<const bf16x8*>(pBW + (size_t)kt * 8192 + 1024);
        bf16x8 b3 = *reinterpret_cast<const bf16x8*>(pBW + (size_t)kt * 8192 + 1536);
#pragma unroll
        for (int m = 0; m < 8; ++m) {
            const __bf16* ap;
            if (kt < XKT)                    ap = axb + (size_t)m * (T_SZ * 2048) + kt * 512;
            else if (!TWOH || kt - XKT < 8)  ap = ahb + (size_t)m * 4096 + (kt - XKT) * 512;
            else                             ap = ah2b + (size_t)m * 4096 + (kt - XKT - 8) * 512;
            bf16x8 am = *reinterpret_cast<const bf16x8*>(ap);
            acc[0][m] = __builtin_amdgcn_mfma_f32_16x16x32_bf16(am, b0, acc[0][m], 0, 0, 0);
            acc[1][m] = __builtin_amdgcn_mfma_f32_16x16x32_bf16(am, b1, acc[1][m], 0, 0, 0);
            acc[2][m] = __builtin_amdgcn_mfma_f32_16x16x32_bf16(am, b2, acc[2][m], 0, 0, 0);
            acc[3][m] = __builtin_amdgcn_mfma_f32_16x16x32_bf16(am, b3, acc[3][m], 0, 0, 0);
        }
    }

    // ---- fused LSTM cell epilogue ----
    const int hcol = wgn * 64 + wc * 16 + r16;
    float bg[4];
#pragma unroll
    for (int g = 0; g < 4; ++g) bg[g] = bias[g * 256 + hcol];

    float* cf = cF + ((size_t)bidh * 512 + tid) * 32;
    const int kth = hcol >> 5;
    const int lh  = ((hcol >> 3) & 3) * 16;
    const int jh  = r16 & 7;

#pragma unroll
    for (int m = 0; m < 8; ++m) {
        f32x4 zi = acc[0][m], zf = acc[1][m], zg = acc[2][m], zo = acc[3][m];
        f32x4 co;
        if (!FIRST) co = *reinterpret_cast<f32x4*>(cf + m * 4);
        f32x4 cn;
#pragma unroll
        for (int q = 0; q < 4; ++q) {
            if (FIRST) cn[q] = sigm(zi[q] + bg[0]) * tanh_(zg[q] + bg[2]);
            else       cn[q] = sigm(zf[q] + bg[1]) * co[q]
                             + sigm(zi[q] + bg[0]) * tanh_(zg[q] + bg[2]);
            float hv = sigm(zo[q] + bg[3]) * tanh_(cn[q]);
            hOF[((size_t)(R0 + m) * 8 + kth) * 512 + (lh + kq * 4 + q) * 8 + jh] = (__bf16)hv;
            if (writeCrow) {
                int row = rb + wr * 128 + m * 16 + kq * 4 + q;
                crow[(size_t)row * 256 + hcol] = cn[q];
            }
        }
        *reinterpret_cast<f32x4*>(cf + m * 4) = cn;
    }
}

// ---------------- fused step: L2(t) and L1(t+1) are independent given h1(t) ----------------
// __launch_bounds__(512, 2): 256-VGPR cap -> no spill (round-14 lesson: (512,4) halved the
// register file and spilled the 128-VGPR accumulator to scratch, 900 MB/dispatch).
template <int XKT, int KT1, int PHASE, int FIRST2>
__global__ void __launch_bounds__(512, 2)
fused_step(const __bf16* __restrict__ xF, int t,
           const __bf16* __restrict__ h1cur, __bf16* __restrict__ h1nxt,
           const __bf16* __restrict__ h2prv, __bf16* __restrict__ h2cur,
           const __bf16* __restrict__ wp1, const __bf16* __restrict__ wp2,
           const float* __restrict__ b1, const float* __restrict__ b2,
           float* __restrict__ c1F, float* __restrict__ c2F,
           float* __restrict__ c1r, float* __restrict__ c2r)
{
    const int bidh = blockIdx.x & 255;

    if constexpr (PHASE == 0) {
        gemm_nolds<XKT, KT1, XKT, 0, 1>(xF, t + 1, h1cur, nullptr, wp1, b1,
                                        c1F, c1r, h1nxt, bidh, 0);
    } else if constexpr (PHASE == 2) {
        gemm_nolds<16, 16, 0, 1, 0>(xF, t, h1cur, h2prv, wp2, b2,
                                    c2F, c2r, h2cur, bidh, 1);
    } else {
        if ((blockIdx.x >> 8) == 0) {
            constexpr int KT2 = FIRST2 ? 8 : 16;
            gemm_nolds<KT2, 16, 0, 1, FIRST2>(xF, t, h1cur, h2prv, wp2, b2,
                                              c2F, c2r, h2cur, bidh, 0);
        } else {
            gemm_nolds<KT1, KT1, XKT, 0, 0>(xF, t + 1, h1cur, nullptr, wp1, b1,
                                            c1F, c1r, h1nxt, bidh, t + 1 == T_SZ - 1);
        }
    }
}

// ---------------- MFMA head (unchanged; reads row-major c) ----------------
__global__ void __launch_bounds__(128, 4)
head_mfma(const float* __restrict__ c1, const float* __restrict__ c2,
          const __bf16* __restrict__ hp, const float* __restrict__ mub,
          const float* __restrict__ lvb, const float* __restrict__ eps,
          float* __restrict__ omu, float* __restrict__ olv, float* __restrict__ osm,
          __bf16* __restrict__ osb)
{
    const int tid = threadIdx.x;
    const int w = tid >> 6, lane = tid & 63;
    const int r16 = lane & 15, kq = lane >> 4;
    const int rb = blockIdx.x * 64 + w * 32;

    f32x4 acc[4][2];
#pragma unroll
    for (int nt = 0; nt < 4; ++nt)
#pragma unroll
        for (int m = 0; m < 2; ++m) acc[nt][m] = f32x4{0.f, 0.f, 0.f, 0.f};

#pragma unroll
    for (int kt = 0; kt < 16; ++kt) {
        const float* cs = (kt < 8) ? c1 : c2;
        int k = (kt & 7) * 32 + kq * 8;
        bf16x8 a[2];
#pragma unroll
        for (int m = 0; m < 2; ++m) {
            const float* pr = cs + (size_t)(rb + m * 16 + r16) * 256 + k;
            float4 u0 = reinterpret_cast<const float4*>(pr)[0];
            float4 u1 = reinterpret_cast<const float4*>(pr)[1];
            a[m][0]=(__bf16)u0.x; a[m][1]=(__bf16)u0.y; a[m][2]=(__bf16)u0.z; a[m][3]=(__bf16)u0.w;
            a[m][4]=(__bf16)u1.x; a[m][5]=(__bf16)u1.y; a[m][6]=(__bf16)u1.z; a[m][7]=(__bf16)u1.w;
        }
        const __bf16* hb = hp + kt * 2048 + lane * 8;
#pragma unroll
        for (int nt = 0; nt < 4; ++nt) {
            bf16x8 bv = *reinterpret_cast<const bf16x8*>(hb + nt * 512);
            acc[nt][0] = __builtin_amdgcn_mfma_f32_16x16x32_bf16(a[0], bv, acc[nt][0], 0, 0, 0);
            acc[nt][1] = __builtin_amdgcn_mfma_f32_16x16x32_bf16(a[1], bv, acc[nt][1], 0, 0, 0);
        }
    }

#pragma unroll
    for (int m = 0; m < 2; ++m)
#pragma unroll
        for (int q = 0; q < 4; ++q) {
            int row = rb + m * 16 + kq * 4 + q;
#pragma unroll
            for (int z = 0; z < 2; ++z) {
                int zc = z * 16 + r16;
                float mu = acc[z][m][q] + mub[zc];
                float lv = acc[z + 2][m][q] + lvb[zc];
                int idx = row * 32 + zc;
                omu[idx] = mu;
                olv[idx] = lv;
                float s = fmaf(eps[idx], expf(0.5f * lv), mu);
                osm[idx] = s;
                if (osb) osb[idx] = (__bf16)s;
            }
        }
}

extern "C" void kernel_launch(void* const* d_in, const int* in_sizes, int n_in,
                              void* d_out, int out_size, void* d_ws, size_t ws_size,
                              hipStream_t stream)
{
    const float* x    = (const float*)d_in[0];
    const float* eps1 = (const float*)d_in[1];
    const float* eps2 = (const float*)d_in[2];
    const float* z2W1 = (const float*)d_in[3];
    const float* z2U1 = (const float*)d_in[4];
    const float* z2b1 = (const float*)d_in[5];
    const float* z2W2 = (const float*)d_in[6];
    const float* z2U2 = (const float*)d_in[7];
    const float* z2b2 = (const float*)d_in[8];
    const float* z1W1 = (const float*)d_in[9];
    const float* z1U1 = (const float*)d_in[10];
    const float* z1b1 = (const float*)d_in[11];
    const float* z1W2 = (const float*)d_in[12];
    const float* z1U2 = (const float*)d_in[13];
    const float* z1b2 = (const float*)d_in[14];
    const float* mu2W = (const float*)d_in[15];
    const float* mu2b = (const float*)d_in[16];
    const float* lv2W = (const float*)d_in[17];
    const float* lv2b = (const float*)d_in[18];
    const float* mu1W = (const float*)d_in[19];
    const float* mu1b = (const float*)d_in[20];
    const float* lv1W = (const float*)d_in[21];
    const float* lv1b = (const float*)d_in[22];

    char* ws = (char*)d_ws;
    __bf16* wp   = (__bf16*)ws;                        // 3.74 MB
    __bf16* z2sb = (__bf16*)(ws + 4194304);            // 1 MB
    __bf16* xF   = (__bf16*)(ws + 5242880);            // 84 MB fragment-layout x
    __bf16* h1Fa = (__bf16*)(ws + 89128960);           // 8 MB each (fragment-layout h)
    __bf16* h1Fb = (__bf16*)(ws + 97517568);
    __bf16* h2Fa = (__bf16*)(ws + 105906176);
    __bf16* h2Fb = (__bf16*)(ws + 114294784);
    float*  c1F  = (float*)(ws + 122683392);           // fragment c, 16 MB each
    float*  c2F  = (float*)(ws + 139460608);
    float*  c1r  = (float*)(ws + 156237824);           // row-major c for heads
    float*  c2r  = (float*)(ws + 173015040);           // end 189,792,256

    __bf16* h1[2] = {h1Fa, h1Fb};
    __bf16* h2[2] = {h2Fa, h2Fb};

    float* out = (float*)d_out;
    const int BZ = B_SZ * 32;
    float* z1mu = out;           float* z1lv = out + BZ;     float* z1sm = out + 2 * BZ;
    float* z2mu = out + 3 * BZ;  float* z2lv = out + 4 * BZ; float* z2sm = out + 5 * BZ;

    xfrag_k<<<20480, 256, 0, stream>>>(x, xF);
    prep_w<<<7296, 256, 0, stream>>>(z2W1, z2U1, z2W2, z2U2, z1W1, z1U1, z1W2, z1U2,
                                     mu2W, lv2W, mu1W, lv1W, wp);

    // ---- z2 branch (XKT=3, KT1=11) ----
    {
        const __bf16* wpa = wp + OFF_L1Z2;
        const __bf16* wpb = wp + OFF_L2Z2;
        fused_step<3, 11, 0, 0><<<256, 512, 0, stream>>>(xF, -1, h1[0], h1[0], h2[0], h2[0],
                                                         wpa, wpb, z2b1, z2b2, c1F, c2F, c1r, c2r);
        fused_step<3, 11, 1, 1><<<512, 512, 0, stream>>>(xF, 0, h1[0], h1[1], h2[1], h2[0],
                                                         wpa, wpb, z2b1, z2b2, c1F, c2F, c1r, c2r);
        for (int t = 1; t < T_SZ - 1; ++t)
            fused_step<3, 11, 1, 0><<<512, 512, 0, stream>>>(xF, t, h1[t & 1], h1[(t + 1) & 1],
                                                             h2[(t + 1) & 1], h2[t & 1],
                                                             wpa, wpb, z2b1, z2b2, c1F, c2F, c1r, c2r);
        fused_step<3, 11, 2, 0><<<256, 512, 0, stream>>>(xF, 19, h1[1], h1[0], h2[0], h2[1],
                                                         wpa, wpb, z2b1, z2b2, c1F, c2F, c1r, c2r);
    }
    head_mfma<<<256, 128, 0, stream>>>(c1r, c2r, wp + OFF_HZ2, mu2b, lv2b, eps2,
                                       z2mu, z2lv, z2sm, z2sb);
    bcast_z2F<<<1280, 256, 0, stream>>>(z2sb, xF);

    // ---- z1 branch (XKT=4, KT1=12) ----
    {
        const __bf16* wpa = wp + OFF_L1Z1;
        const __bf16* wpb = wp + OFF_L2Z1;
        fused_step<4, 12, 0, 0><<<256, 512, 0, stream>>>(xF, -1, h1[0], h1[0], h2[0], h2[0],
                                                         wpa, wpb, z1b1, z1b2, c1F, c2F, c1r, c2r);
        fused_step<4, 12, 1, 1><<<512, 512, 0, stream>>>(xF, 0, h1[0], h1[1], h2[1], h2[0],
                                                         wpa, wpb, z1b1, z1b2, c1F, c2F, c1r, c2r);
        for (int t = 1; t < T_SZ - 1; ++t)
            fused_step<4, 12, 1, 0><<<512, 512, 0, stream>>>(xF, t, h1[t & 1], h1[(t + 1) & 1],
                                                             h2[(t + 1) & 1], h2[t & 1],
                                                             wpa, wpb, z1b1, z1b2, c1F, c2F, c1r, c2r);
        fused_step<4, 12, 2, 0><<<256, 512, 0, stream>>>(xF, 19, h1[1], h1[0], h2[0], h2[1],
                                                         wpa, wpb, z1b1, z1b2, c1F, c2F, c1r, c2r);
    }
    head_mfma<<<256, 128, 0, stream>>>(c1r, c2r, wp + OFF_HZ1, mu1b, lv1b, eps1,
                                       z1mu, z1lv, z1sm, nullptr);
}

// Round 16
// 2096.140 us; speedup vs baseline: 5.5475x; 1.5579x over previous
//
#include <hip/hip_runtime.h>
#include <hip/hip_bf16.h>

#define B_SZ 16384
#define T_SZ 20

typedef __attribute__((ext_vector_type(8))) __bf16 bf16x8;
typedef __attribute__((ext_vector_type(4))) float f32x4;

__device__ __forceinline__ float sigm(float x){ return 1.f/(1.f+__expf(-x)); }
__device__ __forceinline__ float tanh_(float x){ return 1.f-2.f/(__expf(2.f*x)+1.f); }

// packed weight element offsets (bf16 elements)
#define OFF_L1Z2 0
#define OFF_L2Z2 360448
#define OFF_L1Z1 884736
#define OFF_L2Z1 1277952
#define OFF_HZ2  1802240
#define OFF_HZ1  1835008
#define WP_TOT   1867776

// ---------------- weight prep (4-wgn layout, proven) ----------------
__global__ void prep_w(const float* __restrict__ W0, const float* __restrict__ U0,
                       const float* __restrict__ W1, const float* __restrict__ U1,
                       const float* __restrict__ W2, const float* __restrict__ U2,
                       const float* __restrict__ W3, const float* __restrict__ U3,
                       const float* __restrict__ muW2, const float* __restrict__ lvW2,
                       const float* __restrict__ muW1, const float* __restrict__ lvW1,
                       __bf16* __restrict__ wp)
{
    int idx = blockIdx.x * 256 + threadIdx.x;
    if (idx >= WP_TOT) return;
    if (idx < OFF_HZ2) {
        const float *W, *U;
        int Fx, Kx, KT, local;
        if (idx < OFF_L2Z2)      { W = W0; U = U0; Fx = 80;  Kx = 96;  KT = 11; local = idx; }
        else if (idx < OFF_L1Z1) { W = W1; U = U1; Fx = 256; Kx = 256; KT = 16; local = idx - OFF_L2Z2; }
        else if (idx < OFF_L2Z1) { W = W2; U = U2; Fx = 112; Kx = 128; KT = 12; local = idx - OFF_L1Z1; }
        else                     { W = W3; U = U3; Fx = 256; Kx = 256; KT = 16; local = idx - OFF_L2Z1; }
        int jj = local & 7, lane = (local >> 3) & 63, nt16 = (local >> 9) & 15, rest = local >> 13;
        int kt = rest % KT, wgn = rest / KT;
        int gate = nt16 & 3, hh = nt16 >> 2;
        int n = gate * 256 + wgn * 64 + hh * 16 + (lane & 15);
        int k = kt * 32 + ((lane >> 4) << 3) + jj;
        float v = (k < Fx) ? W[k * 1024 + n] : (k < Kx ? 0.f : U[(k - Kx) * 1024 + n]);
        wp[idx] = (__bf16)v;
    } else {
        int base = (idx < OFF_HZ1) ? OFF_HZ2 : OFF_HZ1;
        const float* mw = (idx < OFF_HZ1) ? muW2 : muW1;
        const float* lw = (idx < OFF_HZ1) ? lvW2 : lvW1;
        int local = idx - base;
        int jj = local & 7, lane = (local >> 3) & 63, nt = (local >> 9) & 3, kt = local >> 11;
        int k = kt * 32 + ((lane >> 4) << 3) + jj;
        int c16 = lane & 15;
        float v = (nt < 2) ? mw[k * 32 + nt * 16 + c16] : lw[k * 32 + (nt - 2) * 16 + c16];
        wp[idx] = (__bf16)v;
    }
}

// ---------------- x fp32 -> xb bf16 [B][T][128] (cols >=80 zero) ----------------
__global__ void xconv(const float* __restrict__ x, __bf16* __restrict__ xb)
{
    int idx = blockIdx.x * 256 + threadIdx.x;
    int c8 = idx & 15, row = idx >> 4;
    bf16x8 r;
    if (c8 < 10) {
        const float4* p = reinterpret_cast<const float4*>(x + (size_t)row * 80 + c8 * 8);
        float4 u0 = p[0], u1 = p[1];
        r[0]=(__bf16)u0.x; r[1]=(__bf16)u0.y; r[2]=(__bf16)u0.z; r[3]=(__bf16)u0.w;
        r[4]=(__bf16)u1.x; r[5]=(__bf16)u1.y; r[6]=(__bf16)u1.z; r[7]=(__bf16)u1.w;
    } else {
#pragma unroll
        for (int i = 0; i < 8; ++i) r[i] = (__bf16)0.f;
    }
    *reinterpret_cast<bf16x8*>(xb + (size_t)row * 128 + c8 * 8) = r;
}

// ---------------- broadcast z2 sample into xb cols 80..111 for all t ----------------
__global__ void bcast_z2(const __bf16* __restrict__ z2sb, __bf16* __restrict__ xb)
{
    int idx = blockIdx.x * 256 + threadIdx.x;
    int g = idx & 3, b = idx >> 2;
    bf16x8 v = *reinterpret_cast<const bf16x8*>(z2sb + (size_t)b * 32 + g * 8);
#pragma unroll
    for (int t = 0; t < T_SZ; ++t)
        *reinterpret_cast<bf16x8*>(xb + ((size_t)b * T_SZ + t) * 128 + 80 + g * 8) = v;
}

// ---------------- async 16B global -> LDS ----------------
__device__ __forceinline__ void stage16(const __bf16* g, __bf16* l)
{
    __builtin_amdgcn_global_load_lds(
        (const __attribute__((address_space(1))) unsigned*)g,
        (__attribute__((address_space(3))) unsigned*)l, 16, 0, 0);
}

// ---------------- one LSTM-layer GEMM + cell epilogue ----------------
// wg tile 256 rows x 256 packed cols; block 512 = 8 waves, NOW (wr 0..3, wc 0..1):
// wave = 64 rows x 128 cols (A-LDS bytes/MFMA halved vs the 2x4 split: 128B vs 256B;
// per-CU-phase LDS read 512 cyc < MFMA 620 cyc).  bidh = wgn*64 + mid.
// A: LDS ring-3 ([256][32] lane-linear via global_load_lds, per-lane global src), 1 phase ahead.
// B: global->VGPR ring-2 x 8 frags, 1 phase ahead.  vmcnt(10) = 2 STG_A + 8 LDB of the
// current phase's issues (FIFO: drains prior phase's 10 -> A(K), B(K) complete).
template <int KT, int KTP, int XKT, int TWOH, int FIRST>
__device__ __forceinline__ void gemm_step(const __bf16* __restrict__ xb, int t,
          const __bf16* __restrict__ hA, const __bf16* __restrict__ hB,
          const __bf16* __restrict__ wpm, const float* __restrict__ bias,
          float* __restrict__ cbuf, __bf16* __restrict__ hout,
          __bf16 (&As)[3][8192], int bidh)
{
    const int tid = threadIdx.x;
    const int w = tid >> 6, lane = tid & 63;
    const int r16 = lane & 15, kq = lane >> 4;
    const int wr = w >> 1, wc = w & 1;
    const int mid = bidh & 63, wgn = bidh >> 6;
    const int rb = mid * 256;
    const __bf16* wpB = wpm + (size_t)wgn * KTP * 8192;
    const __bf16* pBW = wpB + wc * 4096 + lane * 8;

    const int srow0 = rb + w * 32 + (lane >> 2);
    const int ksub  = (lane & 3) * 8;
    const __bf16* pA0 = hA + (size_t)srow0 * 256 + ksub;
    const __bf16* pA1 = hA + (size_t)(srow0 + 16) * 256 + ksub;
    const __bf16* px0 = (XKT > 0) ? xb + ((size_t)srow0 * T_SZ + t) * 128 + ksub : pA0;
    const __bf16* px1 = (XKT > 0) ? xb + ((size_t)(srow0 + 16) * T_SZ + t) * 128 + ksub : pA1;
    const __bf16* pH0 = TWOH ? hB + (size_t)srow0 * 256 + ksub : pA0;
    const __bf16* pH1 = TWOH ? hB + (size_t)(srow0 + 16) * 256 + ksub : pA1;

    f32x4 acc[8][4];                       // [j = hh_l*4 + gate][m]
#pragma unroll
    for (int j = 0; j < 8; ++j)
#pragma unroll
        for (int m = 0; m < 4; ++m) acc[j][m] = f32x4{0.f, 0.f, 0.f, 0.f};

    bf16x8 bR[2][8];

#define ASRC(K, P0, PA, PH_) \
    ((K) < XKT ? (P0) + (K) * 32 \
               : ((!TWOH || ((K) - XKT) < 8) ? (PA) + ((K) - XKT) * 32 \
                                             : (PH_) + ((K) - XKT - 8) * 32))
#define STG_A(K) { stage16(ASRC(K, px0, pA0, pH0), &As[(K) % 3][w * 1024]); \
                   stage16(ASRC(K, px1, pA1, pH1), &As[(K) % 3][w * 1024 + 512]); }
#define LDB(K) { _Pragma("unroll") for (int nt = 0; nt < 8; ++nt) \
                   bR[(K) & 1][nt] = *reinterpret_cast<const bf16x8*>(pBW + (size_t)(K) * 8192 + nt * 512); }
#define CMP(K) { const __bf16* ab_ = &As[(K) % 3][(wr * 64 + r16) * 32 + kq * 8]; \
    bf16x8 a_[4]; \
    _Pragma("unroll") for (int m = 0; m < 4; ++m) \
        a_[m] = *reinterpret_cast<const bf16x8*>(ab_ + m * 512); \
    _Pragma("unroll") for (int m = 0; m < 4; ++m) \
        _Pragma("unroll") for (int j = 0; j < 8; ++j) \
            acc[j][m] = __builtin_amdgcn_mfma_f32_16x16x32_bf16(a_[m], bR[(K) & 1][j], acc[j][m], 0, 0, 0); }
#define PH(K) if constexpr ((K) < KT) { \
    __builtin_amdgcn_sched_barrier(0); \
    if constexpr ((K) + 1 < KT) { STG_A((K) + 1); LDB((K) + 1); } \
    { constexpr int c_ = ((K) + 1 < KT) ? 10 : 0; \
      asm volatile("s_waitcnt vmcnt(%0)" :: "n"(c_) : "memory"); } \
    __builtin_amdgcn_s_barrier(); \
    __builtin_amdgcn_sched_barrier(0); \
    CMP(K); }

    // prologue: stage kt 0 (A + B)
    STG_A(0); LDB(0);

    PH(0)  PH(1)  PH(2)  PH(3)  PH(4)  PH(5)  PH(6)  PH(7)
    PH(8)  PH(9)  PH(10) PH(11) PH(12) PH(13) PH(14) PH(15)

#undef ASRC
#undef STG_A
#undef LDB
#undef CMP
#undef PH

    // ---- fused LSTM cell epilogue (wave owns 32 h-cols as 2 hh-groups, 4 gates lane-local) ----
    const int hcb = wgn * 64 + wc * 32;
    float bg[2][4];
#pragma unroll
    for (int hh = 0; hh < 2; ++hh)
#pragma unroll
        for (int g = 0; g < 4; ++g) bg[hh][g] = bias[g * 256 + hcb + hh * 16 + r16];

#pragma unroll
    for (int m = 0; m < 4; ++m)
#pragma unroll
        for (int hh = 0; hh < 2; ++hh) {
            const int hcol = hcb + hh * 16 + r16;
            f32x4 zi = acc[hh * 4 + 0][m], zf = acc[hh * 4 + 1][m];
            f32x4 zg = acc[hh * 4 + 2][m], zo = acc[hh * 4 + 3][m];
#pragma unroll
            for (int q = 0; q < 4; ++q) {
                int row = rb + wr * 64 + m * 16 + kq * 4 + q;
                size_t off = (size_t)row * 256 + hcol;
                float cn;
                if (FIRST) {
                    cn = sigm(zi[q] + bg[hh][0]) * tanh_(zg[q] + bg[hh][2]);
                } else {
                    float co = cbuf[off];
                    cn = sigm(zf[q] + bg[hh][1]) * co + sigm(zi[q] + bg[hh][0]) * tanh_(zg[q] + bg[hh][2]);
                }
                cbuf[off] = cn;
                hout[off] = (__bf16)(sigm(zo[q] + bg[hh][3]) * tanh_(cn));
            }
        }
}

// ---------------- fused step: L2(t) and L1(t+1) are independent given h1(t) ----------------
template <int XKT, int KT1, int PHASE, int FIRST2>
__global__ void __launch_bounds__(512, 2)
fused_step(const __bf16* __restrict__ xb, int t,
           const __bf16* __restrict__ h1cur, __bf16* __restrict__ h1nxt,
           const __bf16* __restrict__ h2prv, __bf16* __restrict__ h2cur,
           const __bf16* __restrict__ wp1, const __bf16* __restrict__ wp2,
           const float* __restrict__ b1, const float* __restrict__ b2,
           float* __restrict__ c1, float* __restrict__ c2)
{
    __shared__ __align__(16) __bf16 As[3][8192];
    const int bidh = blockIdx.x & 255;

    if constexpr (PHASE == 0) {
        gemm_step<XKT, KT1, XKT, 0, 1>(xb, t + 1, h1cur, nullptr, wp1, b1, c1, h1nxt, As, bidh);
    } else if constexpr (PHASE == 2) {
        gemm_step<16, 16, 0, 1, 0>(xb, t, h1cur, h2prv, wp2, b2, c2, h2cur, As, bidh);
    } else {
        if ((blockIdx.x >> 8) == 0) {
            constexpr int KT2 = FIRST2 ? 8 : 16;
            gemm_step<KT2, 16, 0, 1, FIRST2>(xb, t, h1cur, h2prv, wp2, b2, c2, h2cur, As, bidh);
        } else {
            gemm_step<KT1, KT1, XKT, 0, 0>(xb, t + 1, h1cur, nullptr, wp1, b1, c1, h1nxt, As, bidh);
        }
    }
}

// ---------------- MFMA head (unchanged; reads row-major c) ----------------
__global__ void __launch_bounds__(128, 4)
head_mfma(const float* __restrict__ c1, const float* __restrict__ c2,
          const __bf16* __restrict__ hp, const float* __restrict__ mub,
          const float* __restrict__ lvb, const float* __restrict__ eps,
          float* __restrict__ omu, float* __restrict__ olv, float* __restrict__ osm,
          __bf16* __restrict__ osb)
{
    const int tid = threadIdx.x;
    const int w = tid >> 6, lane = tid & 63;
    const int r16 = lane & 15, kq = lane >> 4;
    const int rb = blockIdx.x * 64 + w * 32;

    f32x4 acc[4][2];
#pragma unroll
    for (int nt = 0; nt < 4; ++nt)
#pragma unroll
        for (int m = 0; m < 2; ++m) acc[nt][m] = f32x4{0.f, 0.f, 0.f, 0.f};

#pragma unroll
    for (int kt = 0; kt < 16; ++kt) {
        const float* cs = (kt < 8) ? c1 : c2;
        int k = (kt & 7) * 32 + kq * 8;
        bf16x8 a[2];
#pragma unroll
        for (int m = 0; m < 2; ++m) {
            const float* pr = cs + (size_t)(rb + m * 16 + r16) * 256 + k;
            float4 u0 = reinterpret_cast<const float4*>(pr)[0];
            float4 u1 = reinterpret_cast<const float4*>(pr)[1];
            a[m][0]=(__bf16)u0.x; a[m][1]=(__bf16)u0.y; a[m][2]=(__bf16)u0.z; a[m][3]=(__bf16)u0.w;
            a[m][4]=(__bf16)u1.x; a[m][5]=(__bf16)u1.y; a[m][6]=(__bf16)u1.z; a[m][7]=(__bf16)u1.w;
        }
        const __bf16* hb = hp + kt * 2048 + lane * 8;
#pragma unroll
        for (int nt = 0; nt < 4; ++nt) {
            bf16x8 bv = *reinterpret_cast<const bf16x8*>(hb + nt * 512);
            acc[nt][0] = __builtin_amdgcn_mfma_f32_16x16x32_bf16(a[0], bv, acc[nt][0], 0, 0, 0);
            acc[nt][1] = __builtin_amdgcn_mfma_f32_16x16x32_bf16(a[1], bv, acc[nt][1], 0, 0, 0);
        }
    }

#pragma unroll
    for (int m = 0; m < 2; ++m)
#pragma unroll
        for (int q = 0; q < 4; ++q) {
            int row = rb + m * 16 + kq * 4 + q;
#pragma unroll
            for (int z = 0; z < 2; ++z) {
                int zc = z * 16 + r16;
                float mu = acc[z][m][q] + mub[zc];
                float lv = acc[z + 2][m][q] + lvb[zc];
                int idx = row * 32 + zc;
                omu[idx] = mu;
                olv[idx] = lv;
                float s = fmaf(eps[idx], expf(0.5f * lv), mu);
                osm[idx] = s;
                if (osb) osb[idx] = (__bf16)s;
            }
        }
}

extern "C" void kernel_launch(void* const* d_in, const int* in_sizes, int n_in,
                              void* d_out, int out_size, void* d_ws, size_t ws_size,
                              hipStream_t stream)
{
    const float* x    = (const float*)d_in[0];
    const float* eps1 = (const float*)d_in[1];
    const float* eps2 = (const float*)d_in[2];
    const float* z2W1 = (const float*)d_in[3];
    const float* z2U1 = (const float*)d_in[4];
    const float* z2b1 = (const float*)d_in[5];
    const float* z2W2 = (const float*)d_in[6];
    const float* z2U2 = (const float*)d_in[7];
    const float* z2b2 = (const float*)d_in[8];
    const float* z1W1 = (const float*)d_in[9];
    const float* z1U1 = (const float*)d_in[10];
    const float* z1b1 = (const float*)d_in[11];
    const float* z1W2 = (const float*)d_in[12];
    const float* z1U2 = (const float*)d_in[13];
    const float* z1b2 = (const float*)d_in[14];
    const float* mu2W = (const float*)d_in[15];
    const float* mu2b = (const float*)d_in[16];
    const float* lv2W = (const float*)d_in[17];
    const float* lv2b = (const float*)d_in[18];
    const float* mu1W = (const float*)d_in[19];
    const float* mu1b = (const float*)d_in[20];
    const float* lv1W = (const float*)d_in[21];
    const float* lv1b = (const float*)d_in[22];

    char* ws = (char*)d_ws;
    __bf16* wp   = (__bf16*)ws;                        // 3.74 MB
    __bf16* z2sb = (__bf16*)(ws + 4194304);            // 1 MB
    __bf16* xb   = (__bf16*)(ws + 5242880);            // 80 MB
    __bf16* h1a  = (__bf16*)(ws + 89128960);           // 8 MB each
    __bf16* h1b  = (__bf16*)(ws + 97517568);
    __bf16* h2a  = (__bf16*)(ws + 105906176);
    __bf16* h2b  = (__bf16*)(ws + 114294784);
    float*  c1   = (float*)(ws + 122683392);           // 16 MB each
    float*  c2   = (float*)(ws + 139460608);           // end 156,237,824

    __bf16* h1[2] = {h1a, h1b};
    __bf16* h2[2] = {h2a, h2b};

    float* out = (float*)d_out;
    const int BZ = B_SZ * 32;
    float* z1mu = out;           float* z1lv = out + BZ;     float* z1sm = out + 2 * BZ;
    float* z2mu = out + 3 * BZ;  float* z2lv = out + 4 * BZ; float* z2sm = out + 5 * BZ;

    xconv<<<B_SZ * T_SZ * 16 / 256, 256, 0, stream>>>(x, xb);
    prep_w<<<7296, 256, 0, stream>>>(z2W1, z2U1, z2W2, z2U2, z1W1, z1U1, z1W2, z1U2,
                                     mu2W, lv2W, mu1W, lv1W, wp);

    // ---- z2 branch (XKT=3, KT1=11) ----
    {
        const __bf16* wpa = wp + OFF_L1Z2;
        const __bf16* wpb = wp + OFF_L2Z2;
        fused_step<3, 11, 0, 0><<<256, 512, 0, stream>>>(xb, -1, h1[0], h1[0], h2[0], h2[0],
                                                         wpa, wpb, z2b1, z2b2, c1, c2);
        fused_step<3, 11, 1, 1><<<512, 512, 0, stream>>>(xb, 0, h1[0], h1[1], h2[1], h2[0],
                                                         wpa, wpb, z2b1, z2b2, c1, c2);
        for (int t = 1; t < T_SZ - 1; ++t)
            fused_step<3, 11, 1, 0><<<512, 512, 0, stream>>>(xb, t, h1[t & 1], h1[(t + 1) & 1],
                                                             h2[(t + 1) & 1], h2[t & 1],
                                                             wpa, wpb, z2b1, z2b2, c1, c2);
        fused_step<3, 11, 2, 0><<<256, 512, 0, stream>>>(xb, 19, h1[1], h1[0], h2[0], h2[1],
                                                         wpa, wpb, z2b1, z2b2, c1, c2);
    }
    head_mfma<<<256, 128, 0, stream>>>(c1, c2, wp + OFF_HZ2, mu2b, lv2b, eps2,
                                       z2mu, z2lv, z2sm, z2sb);
    bcast_z2<<<B_SZ * 4 / 256, 256, 0, stream>>>(z2sb, xb);

    // ---- z1 branch (XKT=4, KT1=12) ----
    {
        const __bf16* wpa = wp + OFF_L1Z1;
        const __bf16* wpb = wp + OFF_L2Z1;
        fused_step<4, 12, 0, 0><<<256, 512, 0, stream>>>(xb, -1, h1[0], h1[0], h2[0], h2[0],
                                                         wpa, wpb, z1b1, z1b2, c1, c2);
        fused_step<4, 12, 1, 1><<<512, 512, 0, stream>>>(xb, 0, h1[0], h1[1], h2[1], h2[0],
                                                         wpa, wpb, z1b1, z1b2, c1, c2);
        for (int t = 1; t < T_SZ - 1; ++t)
            fused_step<4, 12, 1, 0><<<512, 512, 0, stream>>>(xb, t, h1[t & 1], h1[(t + 1) & 1],
                                                             h2[(t + 1) & 1], h2[t & 1],
                                                             wpa, wpb, z1b1, z1b2, c1, c2);
        fused_step<4, 12, 2, 0><<<256, 512, 0, stream>>>(xb, 19, h1[1], h1[0], h2[0], h2[1],
                                                         wpa, wpb, z1b1, z1b2, c1, c2);
    }
    head_mfma<<<256, 128, 0, stream>>>(c1, c2, wp + OFF_HZ1, mu1b, lv1b, eps1,
                                       z1mu, z1lv, z1sm, nullptr);
}

// Round 17
// 2069.441 us; speedup vs baseline: 5.6191x; 1.0129x over previous
//
#include <hip/hip_runtime.h>
#include <hip/hip_bf16.h>

#define B_SZ 16384
#define T_SZ 20

typedef __attribute__((ext_vector_type(8))) __bf16 bf16x8;
typedef __attribute__((ext_vector_type(4))) float f32x4;

__device__ __forceinline__ float sigm(float x){ return 1.f/(1.f+__expf(-x)); }
__device__ __forceinline__ float tanh_(float x){ return 1.f-2.f/(__expf(2.f*x)+1.f); }

// packed weight element offsets (bf16 elements)
#define OFF_L1Z2 0
#define OFF_L2Z2 360448
#define OFF_L1Z1 884736
#define OFF_L2Z1 1277952
#define OFF_HZ2  1802240
#define OFF_HZ1  1835008
#define WP_TOT   1867776

// ---------------- weight prep (4-wgn layout, proven) ----------------
__global__ void prep_w(const float* __restrict__ W0, const float* __restrict__ U0,
                       const float* __restrict__ W1, const float* __restrict__ U1,
                       const float* __restrict__ W2, const float* __restrict__ U2,
                       const float* __restrict__ W3, const float* __restrict__ U3,
                       const float* __restrict__ muW2, const float* __restrict__ lvW2,
                       const float* __restrict__ muW1, const float* __restrict__ lvW1,
                       __bf16* __restrict__ wp)
{
    int idx = blockIdx.x * 256 + threadIdx.x;
    if (idx >= WP_TOT) return;
    if (idx < OFF_HZ2) {
        const float *W, *U;
        int Fx, Kx, KT, local;
        if (idx < OFF_L2Z2)      { W = W0; U = U0; Fx = 80;  Kx = 96;  KT = 11; local = idx; }
        else if (idx < OFF_L1Z1) { W = W1; U = U1; Fx = 256; Kx = 256; KT = 16; local = idx - OFF_L2Z2; }
        else if (idx < OFF_L2Z1) { W = W2; U = U2; Fx = 112; Kx = 128; KT = 12; local = idx - OFF_L1Z1; }
        else                     { W = W3; U = U3; Fx = 256; Kx = 256; KT = 16; local = idx - OFF_L2Z1; }
        int jj = local & 7, lane = (local >> 3) & 63, nt16 = (local >> 9) & 15, rest = local >> 13;
        int kt = rest % KT, wgn = rest / KT;
        int gate = nt16 & 3, hh = nt16 >> 2;
        int n = gate * 256 + wgn * 64 + hh * 16 + (lane & 15);
        int k = kt * 32 + ((lane >> 4) << 3) + jj;
        float v = (k < Fx) ? W[k * 1024 + n] : (k < Kx ? 0.f : U[(k - Kx) * 1024 + n]);
        wp[idx] = (__bf16)v;
    } else {
        int base = (idx < OFF_HZ1) ? OFF_HZ2 : OFF_HZ1;
        const float* mw = (idx < OFF_HZ1) ? muW2 : muW1;
        const float* lw = (idx < OFF_HZ1) ? lvW2 : lvW1;
        int local = idx - base;
        int jj = local & 7, lane = (local >> 3) & 63, nt = (local >> 9) & 3, kt = local >> 11;
        int k = kt * 32 + ((lane >> 4) << 3) + jj;
        int c16 = lane & 15;
        float v = (nt < 2) ? mw[k * 32 + nt * 16 + c16] : lw[k * 32 + (nt - 2) * 16 + c16];
        wp[idx] = (__bf16)v;
    }
}

// ---------------- x fp32 -> xb bf16 [B][T][128] (cols >=80 zero) ----------------
__global__ void xconv(const float* __restrict__ x, __bf16* __restrict__ xb)
{
    int idx = blockIdx.x * 256 + threadIdx.x;
    int c8 = idx & 15, row = idx >> 4;
    bf16x8 r;
    if (c8 < 10) {
        const float4* p = reinterpret_cast<const float4*>(x + (size_t)row * 80 + c8 * 8);
        float4 u0 = p[0], u1 = p[1];
        r[0]=(__bf16)u0.x; r[1]=(__bf16)u0.y; r[2]=(__bf16)u0.z; r[3]=(__bf16)u0.w;
        r[4]=(__bf16)u1.x; r[5]=(__bf16)u1.y; r[6]=(__bf16)u1.z; r[7]=(__bf16)u1.w;
    } else {
#pragma unroll
        for (int i = 0; i < 8; ++i) r[i] = (__bf16)0.f;
    }
    *reinterpret_cast<bf16x8*>(xb + (size_t)row * 128 + c8 * 8) = r;
}

// ---------------- broadcast z2 sample into xb cols 80..111 for all t ----------------
__global__ void bcast_z2(const __bf16* __restrict__ z2sb, __bf16* __restrict__ xb)
{
    int idx = blockIdx.x * 256 + threadIdx.x;
    int g = idx & 3, b = idx >> 2;
    bf16x8 v = *reinterpret_cast<const bf16x8*>(z2sb + (size_t)b * 32 + g * 8);
#pragma unroll
    for (int t = 0; t < T_SZ; ++t)
        *reinterpret_cast<bf16x8*>(xb + ((size_t)b * T_SZ + t) * 128 + 80 + g * 8) = v;
}

// ---------------- async 16B global -> LDS ----------------
__device__ __forceinline__ void stage16(const __bf16* g, __bf16* l)
{
    __builtin_amdgcn_global_load_lds(
        (const __attribute__((address_space(1))) unsigned*)g,
        (__attribute__((address_space(3))) unsigned*)l, 16, 0, 0);
}

// ---------------- one LSTM-layer GEMM + cell epilogue (round-11 proven body) ----------------
// wg tile 256 rows x 256 packed cols; bidh = wgn*64 + mid.  block 512 = 8 waves (wr 0..1, wc 0..3).
// A staged in LDS ring-3 ([256][32] lane-linear, per-lane global src); B global->VGPR ring-3,
// 2 phases ahead; counted vmcnt = 2*(STG k+1 pending) + 4*(LDB k+2 pending); 1 barrier/phase.
template <int KT, int KTP, int XKT, int TWOH, int FIRST>
__device__ __forceinline__ void gemm_step(const __bf16* __restrict__ xb, int t,
          const __bf16* __restrict__ hA, const __bf16* __restrict__ hB,
          const __bf16* __restrict__ wpm, const float* __restrict__ bias,
          float* __restrict__ cbuf, __bf16* __restrict__ hout,
          __bf16 (&As)[3][8192], int bidh)
{
    const int tid = threadIdx.x;
    const int w = tid >> 6, lane = tid & 63;
    const int r16 = lane & 15, kq = lane >> 4;
    const int wr = w >> 2, wc = w & 3;
    const int mid = bidh & 63, wgn = bidh >> 6;
    const int rb = mid * 256;
    const __bf16* wpB = wpm + (size_t)wgn * KTP * 8192;
    const __bf16* pBW = wpB + wc * 2048 + lane * 8;

    const int srow0 = rb + w * 32 + (lane >> 2);
    const int ksub  = (lane & 3) * 8;
    const __bf16* pA0 = hA + (size_t)srow0 * 256 + ksub;
    const __bf16* pA1 = hA + (size_t)(srow0 + 16) * 256 + ksub;
    const __bf16* px0 = (XKT > 0) ? xb + ((size_t)srow0 * T_SZ + t) * 128 + ksub : pA0;
    const __bf16* px1 = (XKT > 0) ? xb + ((size_t)(srow0 + 16) * T_SZ + t) * 128 + ksub : pA1;
    const __bf16* pH0 = TWOH ? hB + (size_t)srow0 * 256 + ksub : pA0;
    const __bf16* pH1 = TWOH ? hB + (size_t)(srow0 + 16) * 256 + ksub : pA1;

    f32x4 acc[4][8];
#pragma unroll
    for (int g = 0; g < 4; ++g)
#pragma unroll
        for (int m = 0; m < 8; ++m) acc[g][m] = f32x4{0.f, 0.f, 0.f, 0.f};

    bf16x8 bR[3][4];

#define ASRC(K, P0, PA, PH_) \
    ((K) < XKT ? (P0) + (K) * 32 \
               : ((!TWOH || ((K) - XKT) < 8) ? (PA) + ((K) - XKT) * 32 \
                                             : (PH_) + ((K) - XKT - 8) * 32))
#define STG_A(K) { stage16(ASRC(K, px0, pA0, pH0), &As[(K) % 3][w * 1024]); \
                   stage16(ASRC(K, px1, pA1, pH1), &As[(K) % 3][w * 1024 + 512]); }
#define LDB(K) { _Pragma("unroll") for (int nt = 0; nt < 4; ++nt) \
                   bR[(K) % 3][nt] = *reinterpret_cast<const bf16x8*>(pBW + (size_t)(K) * 8192 + nt * 512); }
#define CMP(K) { const __bf16* ab_ = &As[(K) % 3][(wr * 128 + r16) * 32 + kq * 8]; \
    bf16x8 a_[8]; \
    _Pragma("unroll") for (int m = 0; m < 8; ++m) \
        a_[m] = *reinterpret_cast<const bf16x8*>(ab_ + m * 512); \
    _Pragma("unroll") for (int m = 0; m < 8; ++m) \
        _Pragma("unroll") for (int g = 0; g < 4; ++g) \
            acc[g][m] = __builtin_amdgcn_mfma_f32_16x16x32_bf16(a_[m], bR[(K) % 3][g], acc[g][m], 0, 0, 0); }
#define PH(K) if constexpr ((K) < KT) { \
    __builtin_amdgcn_sched_barrier(0); \
    if constexpr ((K) + 1 < KT) STG_A((K) + 1); \
    if constexpr ((K) + 2 < KT) LDB((K) + 2); \
    { constexpr int c_ = 2 * (((K) + 1 < KT) ? 1 : 0) + 4 * (((K) + 2 < KT) ? 1 : 0); \
      asm volatile("s_waitcnt vmcnt(%0)" :: "n"(c_) : "memory"); } \
    __builtin_amdgcn_s_barrier(); \
    __builtin_amdgcn_sched_barrier(0); \
    CMP(K); }

    // prologue
    STG_A(0); LDB(0);
    if constexpr (KT > 1) LDB(1);

    PH(0)  PH(1)  PH(2)  PH(3)  PH(4)  PH(5)  PH(6)  PH(7)
    PH(8)  PH(9)  PH(10) PH(11) PH(12) PH(13) PH(14) PH(15)

#undef ASRC
#undef STG_A
#undef LDB
#undef CMP
#undef PH

    // ---- fused LSTM cell epilogue (wave owns 16 h-cols, all 4 gates lane-local) ----
    const int hcol = wgn * 64 + wc * 16 + r16;
    float bg[4];
#pragma unroll
    for (int g = 0; g < 4; ++g) bg[g] = bias[g * 256 + hcol];

#pragma unroll
    for (int m = 0; m < 8; ++m) {
        f32x4 zi = acc[0][m], zf = acc[1][m], zg = acc[2][m], zo = acc[3][m];
#pragma unroll
        for (int q = 0; q < 4; ++q) {
            int row = rb + wr * 128 + m * 16 + kq * 4 + q;
            size_t off = (size_t)row * 256 + hcol;
            float cn;
            if (FIRST) {
                cn = sigm(zi[q] + bg[0]) * tanh_(zg[q] + bg[2]);
            } else {
                float co = cbuf[off];
                cn = sigm(zf[q] + bg[1]) * co + sigm(zi[q] + bg[0]) * tanh_(zg[q] + bg[2]);
            }
            cbuf[off] = cn;
            hout[off] = (__bf16)(sigm(zo[q] + bg[3]) * tanh_(cn));
        }
    }
}

// ---------------- fused step: L2(t) and L1(t+1) are independent given h1(t) ----------------
template <int XKT, int KT1, int PHASE, int FIRST2>
__global__ void __launch_bounds__(512, 2)
fused_step(const __bf16* __restrict__ xb, int t,
           const __bf16* __restrict__ h1cur, __bf16* __restrict__ h1nxt,
           const __bf16* __restrict__ h2prv, __bf16* __restrict__ h2cur,
           const __bf16* __restrict__ wp1, const __bf16* __restrict__ wp2,
           const float* __restrict__ b1, const float* __restrict__ b2,
           float* __restrict__ c1, float* __restrict__ c2)
{
    __shared__ __align__(16) __bf16 As[3][8192];
    const int bidh = blockIdx.x & 255;

    if constexpr (PHASE == 0) {
        gemm_step<XKT, KT1, XKT, 0, 1>(xb, t + 1, h1cur, nullptr, wp1, b1, c1, h1nxt, As, bidh);
    } else if constexpr (PHASE == 2) {
        gemm_step<16, 16, 0, 1, 0>(xb, t, h1cur, h2prv, wp2, b2, c2, h2cur, As, bidh);
    } else {
        if ((blockIdx.x >> 8) == 0) {
            constexpr int KT2 = FIRST2 ? 8 : 16;
            gemm_step<KT2, 16, 0, 1, FIRST2>(xb, t, h1cur, h2prv, wp2, b2, c2, h2cur, As, bidh);
        } else {
            gemm_step<KT1, KT1, XKT, 0, 0>(xb, t + 1, h1cur, nullptr, wp1, b1, c1, h1nxt, As, bidh);
        }
    }
}

// ---------------- MFMA head (reads row-major c) ----------------
__global__ void __launch_bounds__(128, 4)
head_mfma(const float* __restrict__ c1, const float* __restrict__ c2,
          const __bf16* __restrict__ hp, const float* __restrict__ mub,
          const float* __restrict__ lvb, const float* __restrict__ eps,
          float* __restrict__ omu, float* __restrict__ olv, float* __restrict__ osm,
          __bf16* __restrict__ osb)
{
    const int tid = threadIdx.x;
    const int w = tid >> 6, lane = tid & 63;
    const int r16 = lane & 15, kq = lane >> 4;
    const int rb = blockIdx.x * 64 + w * 32;

    f32x4 acc[4][2];
#pragma unroll
    for (int nt = 0; nt < 4; ++nt)
#pragma unroll
        for (int m = 0; m < 2; ++m) acc[nt][m] = f32x4{0.f, 0.f, 0.f, 0.f};

#pragma unroll
    for (int kt = 0; kt < 16; ++kt) {
        const float* cs = (kt < 8) ? c1 : c2;
        int k = (kt & 7) * 32 + kq * 8;
        bf16x8 a[2];
#pragma unroll
        for (int m = 0; m < 2; ++m) {
            const float* pr = cs + (size_t)(rb + m * 16 + r16) * 256 + k;
            float4 u0 = reinterpret_cast<const float4*>(pr)[0];
            float4 u1 = reinterpret_cast<const float4*>(pr)[1];
            a[m][0]=(__bf16)u0.x; a[m][1]=(__bf16)u0.y; a[m][2]=(__bf16)u0.z; a[m][3]=(__bf16)u0.w;
            a[m][4]=(__bf16)u1.x; a[m][5]=(__bf16)u1.y; a[m][6]=(__bf16)u1.z; a[m][7]=(__bf16)u1.w;
        }
        const __bf16* hb = hp + kt * 2048 + lane * 8;
#pragma unroll
        for (int nt = 0; nt < 4; ++nt) {
            bf16x8 bv = *reinterpret_cast<const bf16x8*>(hb + nt * 512);
            acc[nt][0] = __builtin_amdgcn_mfma_f32_16x16x32_bf16(a[0], bv, acc[nt][0], 0, 0, 0);
            acc[nt][1] = __builtin_amdgcn_mfma_f32_16x16x32_bf16(a[1], bv, acc[nt][1], 0, 0, 0);
        }
    }

#pragma unroll
    for (int m = 0; m < 2; ++m)
#pragma unroll
        for (int q = 0; q < 4; ++q) {
            int row = rb + m * 16 + kq * 4 + q;
#pragma unroll
            for (int z = 0; z < 2; ++z) {
                int zc = z * 16 + r16;
                float mu = acc[z][m][q] + mub[zc];
                float lv = acc[z + 2][m][q] + lvb[zc];
                int idx = row * 32 + zc;
                omu[idx] = mu;
                olv[idx] = lv;
                float s = fmaf(eps[idx], expf(0.5f * lv), mu);
                osm[idx] = s;
                if (osb) osb[idx] = (__bf16)s;
            }
        }
}

extern "C" void kernel_launch(void* const* d_in, const int* in_sizes, int n_in,
                              void* d_out, int out_size, void* d_ws, size_t ws_size,
                              hipStream_t stream)
{
    const float* x    = (const float*)d_in[0];
    const float* eps1 = (const float*)d_in[1];
    const float* eps2 = (const float*)d_in[2];
    const float* z2W1 = (const float*)d_in[3];
    const float* z2U1 = (const float*)d_in[4];
    const float* z2b1 = (const float*)d_in[5];
    const float* z2W2 = (const float*)d_in[6];
    const float* z2U2 = (const float*)d_in[7];
    const float* z2b2 = (const float*)d_in[8];
    const float* z1W1 = (const float*)d_in[9];
    const float* z1U1 = (const float*)d_in[10];
    const float* z1b1 = (const float*)d_in[11];
    const float* z1W2 = (const float*)d_in[12];
    const float* z1U2 = (const float*)d_in[13];
    const float* z1b2 = (const float*)d_in[14];
    const float* mu2W = (const float*)d_in[15];
    const float* mu2b = (const float*)d_in[16];
    const float* lv2W = (const float*)d_in[17];
    const float* lv2b = (const float*)d_in[18];
    const float* mu1W = (const float*)d_in[19];
    const float* mu1b = (const float*)d_in[20];
    const float* lv1W = (const float*)d_in[21];
    const float* lv1b = (const float*)d_in[22];

    char* ws = (char*)d_ws;
    __bf16* wp   = (__bf16*)ws;                        // 3.74 MB
    __bf16* z2sb = (__bf16*)(ws + 4194304);            // 1 MB
    __bf16* xb   = (__bf16*)(ws + 5242880);            // 80 MB
    __bf16* h1a  = (__bf16*)(ws + 89128960);           // 8 MB each
    __bf16* h1b  = (__bf16*)(ws + 97517568);
    __bf16* h2a  = (__bf16*)(ws + 105906176);
    __bf16* h2b  = (__bf16*)(ws + 114294784);
    float*  c1   = (float*)(ws + 122683392);           // 16 MB each
    float*  c2   = (float*)(ws + 139460608);           // end 156,237,824

    __bf16* h1[2] = {h1a, h1b};
    __bf16* h2[2] = {h2a, h2b};

    float* out = (float*)d_out;
    const int BZ = B_SZ * 32;
    float* z1mu = out;           float* z1lv = out + BZ;     float* z1sm = out + 2 * BZ;
    float* z2mu = out + 3 * BZ;  float* z2lv = out + 4 * BZ; float* z2sm = out + 5 * BZ;

    xconv<<<B_SZ * T_SZ * 16 / 256, 256, 0, stream>>>(x, xb);
    prep_w<<<7296, 256, 0, stream>>>(z2W1, z2U1, z2W2, z2U2, z1W1, z1U1, z1W2, z1U2,
                                     mu2W, lv2W, mu1W, lv1W, wp);

    // ---- z2 branch (XKT=3, KT1=11) ----
    {
        const __bf16* wpa = wp + OFF_L1Z2;
        const __bf16* wpb = wp + OFF_L2Z2;
        fused_step<3, 11, 0, 0><<<256, 512, 0, stream>>>(xb, -1, h1[0], h1[0], h2[0], h2[0],
                                                         wpa, wpb, z2b1, z2b2, c1, c2);
        fused_step<3, 11, 1, 1><<<512, 512, 0, stream>>>(xb, 0, h1[0], h1[1], h2[1], h2[0],
                                                         wpa, wpb, z2b1, z2b2, c1, c2);
        for (int t = 1; t < T_SZ - 1; ++t)
            fused_step<3, 11, 1, 0><<<512, 512, 0, stream>>>(xb, t, h1[t & 1], h1[(t + 1) & 1],
                                                             h2[(t + 1) & 1], h2[t & 1],
                                                             wpa, wpb, z2b1, z2b2, c1, c2);
        fused_step<3, 11, 2, 0><<<256, 512, 0, stream>>>(xb, 19, h1[1], h1[0], h2[0], h2[1],
                                                         wpa, wpb, z2b1, z2b2, c1, c2);
    }
    head_mfma<<<256, 128, 0, stream>>>(c1, c2, wp + OFF_HZ2, mu2b, lv2b, eps2,
                                       z2mu, z2lv, z2sm, z2sb);
    bcast_z2<<<B_SZ * 4 / 256, 256, 0, stream>>>(z2sb, xb);

    // ---- z1 branch (XKT=4, KT1=12) ----
    {
        const __bf16* wpa = wp + OFF_L1Z1;
        const __bf16* wpb = wp + OFF_L2Z1;
        fused_step<4, 12, 0, 0><<<256, 512, 0, stream>>>(xb, -1, h1[0], h1[0], h2[0], h2[0],
                                                         wpa, wpb, z1b1, z1b2, c1, c2);
        fused_step<4, 12, 1, 1><<<512, 512, 0, stream>>>(xb, 0, h1[0], h1[1], h2[1], h2[0],
                                                         wpa, wpb, z1b1, z1b2, c1, c2);
        for (int t = 1; t < T_SZ - 1; ++t)
            fused_step<4, 12, 1, 0><<<512, 512, 0, stream>>>(xb, t, h1[t & 1], h1[(t + 1) & 1],
                                                             h2[(t + 1) & 1], h2[t & 1],
                                                             wpa, wpb, z1b1, z1b2, c1, c2);
        fused_step<4, 12, 2, 0><<<256, 512, 0, stream>>>(xb, 19, h1[1], h1[0], h2[0], h2[1],
                                                         wpa, wpb, z1b1, z1b2, c1, c2);
    }
    head_mfma<<<256, 128, 0, stream>>>(c1, c2, wp + OFF_HZ1, mu1b, lv1b, eps1,
                                       z1mu, z1lv, z1sm, nullptr);
}